// Round 8
// baseline (355.243 us; speedup 1.0000x reference)
//
#include <hip/hip_runtime.h>
#include <math.h>

#define B_SZ 2
#define H_IN 256
#define W_IN 256
#define HO 128
#define WO 128
#define CIN 128
#define CO_OFF 1152
#define CO_MSK 576
#define NG 64
#define KD 1152           // GEMM K, reordered: k = (kh*3+kw)*128 + ci
#define KBY 2304          // K row bytes in bf16
#define ND 32768          // GEMM N = B*HO*WO
#define MPAD 1792         // 1728 padded to 14*128
#define NTK 18            // K-tiles (1152/64)
#define XTROW_B 66048     // 258*128*2 bytes per padded iy row (GEMM layout)
#define XTIMG_B 17040384  // 258*XTROW_B bytes per image
#define XT2ROW_B 1032     // 258*2ch*2B per iy row (deform layout, per group)
#define XT2G_B 266256     // 258*XT2ROW_B per (b,g) plane
#define XT2IMG_B 17040384 // 64*XT2G_B per image

typedef short short8 __attribute__((ext_vector_type(8)));
typedef float f32x4 __attribute__((ext_vector_type(4)));
typedef const unsigned int __attribute__((address_space(1))) gcu32;
typedef unsigned int __attribute__((address_space(3))) slu32;

__device__ __forceinline__ unsigned short f2b(float v) {
  union { float f; unsigned u; } a; a.f = v;
  unsigned r = a.u + 0x7FFF + ((a.u >> 16) & 1);
  return (unsigned short)(r >> 16);
}
__device__ __forceinline__ float b2f(unsigned short u) {
  union { unsigned u; float f; } a; a.u = ((unsigned)u) << 16;
  return a.f;
}

// ---------------------------------------------------------------------------
// x (NCHW f32) -> xt  [b][iy+1][ix+1][ci]        bf16 (GEMM B operand)
//              -> xt2 [b][g][iy+1][ix+1][c{0,1}] bf16 (deform gather layout)
// One block per (b, iy_t); full 128ci x 256ix row staged once in LDS (bf16),
// single barrier, both layouts emitted coalesced.
// ---------------------------------------------------------------------------
__global__ __launch_bounds__(256) void xpose(const float* __restrict__ x,
                                             unsigned short* __restrict__ xt,
                                             unsigned short* __restrict__ xt2) {
  const int bid = blockIdx.x;            // 2*258
  const int iyt = bid % 258;
  const int b = bid / 258;
  const int tid = threadIdx.x;
  char* rowp = (char*)xt  + (size_t)b * XTIMG_B  + (size_t)iyt * XTROW_B;
  char* x2b  = (char*)xt2 + (size_t)b * XT2IMG_B + (size_t)iyt * XT2ROW_B;
  const int iy = iyt - 1;
  const short8 z8 = {0, 0, 0, 0, 0, 0, 0, 0};

  if (iy < 0 || iy >= H_IN) {            // full zero row in both tensors
    for (int i = tid; i < 4128; i += 256)
      *reinterpret_cast<short8*>(rowp + i * 16) = z8;
    for (int i = tid; i < 16512; i += 256) {   // 64 g x 258 ix, 4B each
      int g = i / 258, ix = i - g * 258;
      *reinterpret_cast<unsigned*>(x2b + (size_t)g * XT2G_B + ix * 4) = 0u;
    }
    return;
  }
  if (tid < 32) {                        // xt: ix = -1 and 256 pad columns
    int c = tid & 15;
    *reinterpret_cast<short8*>(rowp + ((tid >> 4) ? 257 * 256 : 0) + c * 16) = z8;
  }
  if (tid < 128) {                       // xt2 pad columns: 64 g x 2 cols
    int g = tid >> 1, c = tid & 1;
    *reinterpret_cast<unsigned*>(x2b + (size_t)g * XT2G_B + (c ? 257 : 0) * 4) = 0u;
  }

  __shared__ unsigned short S[128][256];   // 64 KB, [ci][ix] bf16
  const float* xb = x + (size_t)b * CIN * 65536 + (size_t)iy * 256;

  // stage: 128 ci x 64 float4, lane-consecutive ix -> 1KB/instr coalesced
  #pragma unroll
  for (int i = 0; i < 32; i++) {
    int id = i * 256 + tid;
    int ci = id >> 6;
    int f4 = id & 63;
    float4 v = *reinterpret_cast<const float4*>(xb + (size_t)ci * 65536 + f4 * 4);
    unsigned lo = (unsigned)f2b(v.x) | ((unsigned)f2b(v.y) << 16);
    unsigned hi = (unsigned)f2b(v.z) | ((unsigned)f2b(v.w) << 16);
    *reinterpret_cast<uint2*>(&S[ci][f4 * 4]) = make_uint2(lo, hi);
  }
  __syncthreads();

  // xt [ix][ci]: 16 iters x short8 (16B) stores, lane-consecutive ix
  #pragma unroll
  for (int i = 0; i < 16; i++) {
    int id = i * 256 + tid;
    int ix = id & 255, cg = id >> 8;
    short8 o;
    #pragma unroll
    for (int e = 0; e < 8; e++) o[e] = (short)S[cg * 8 + e][ix];
    *reinterpret_cast<short8*>(rowp + (ix + 1) * 256 + cg * 16) = o;
  }

  // xt2 [g][ix][c2]: 64 iters, each instr writes a contiguous 1KB g-row
  #pragma unroll 4
  for (int g = 0; g < 64; g++) {
    unsigned u = (unsigned)S[2 * g][tid] | ((unsigned)S[2 * g + 1][tid] << 16);
    *reinterpret_cast<unsigned*>(x2b + (size_t)g * XT2G_B + (tid + 1) * 4) = u;
  }
}

// ---------------------------------------------------------------------------
// Pack weights bf16 [MPAD][KD], K reordered: wb[m][tap*128+ci] = w[m][ci*9+tap]
// ---------------------------------------------------------------------------
__global__ __launch_bounds__(256) void pack_w(const float* __restrict__ w_off,
                                              const float* __restrict__ w_msk,
                                              unsigned short* __restrict__ wb) {
  int i = blockIdx.x * 256 + threadIdx.x;        // MPAD*KD exact
  int m = i / KD;
  int k = i - m * KD;
  int tap = k >> 7, ci = k & 127;
  int src = ci * 9 + tap;
  float v = 0.f;
  if (m < CO_OFF) v = w_off[(size_t)m * KD + src];
  else if (m < 1728) v = w_msk[(size_t)(m - CO_OFF) * KD + src];
  wb[i] = f2b(v);
}

// ---------------------------------------------------------------------------
// MFMA GEMM (round-2 proven structure): 128x128 tile, BK=64, 4 waves,
// single 32 KiB LDS buffer, sync-stage-sync-compute. B staged directly from
// xt (implicit conv). Both-sides XOR swizzle (row&7)<<4. Epilogue fuses
// bias + sigmoid, bf16 store.
// ---------------------------------------------------------------------------
__global__ __launch_bounds__(256, 2) void gemm_conv(
    const unsigned short* __restrict__ wb, const unsigned short* __restrict__ xt,
    const float* __restrict__ b_off, const float* __restrict__ b_msk,
    unsigned short* __restrict__ offs, unsigned short* __restrict__ mask)
{
  __shared__ __attribute__((aligned(128))) char sA[16384];   // [128 m][64 k] bf16, swizzled
  __shared__ __attribute__((aligned(128))) char sB[16384];   // [128 n][64 k] bf16, swizzled

  // XCD-aware bijective swizzle (3584 % 8 == 0, 448 per XCD)
  const int bid = blockIdx.x;
  const int swz = (bid & 7) * 448 + (bid >> 3);
  const int m0 = (swz % 14) * 128;
  const int n0 = (swz / 14) * 128;
  const int ho = (n0 >> 7) & 127;
  const int b  = n0 >> 14;

  const int tid = threadIdx.x;
  const int l = tid & 63;
  const int w = tid >> 6;

  // staging: waves 0,1 -> A halves; waves 2,3 -> B halves. 8 chunks of 8 rows.
  const int rl = l >> 3;                          // row within chunk
  const int kbsw = ((l & 7) << 4) ^ (rl << 4);    // inverse-swizzled src k-byte
  const char* gA = (const char*)wb + (size_t)(m0 + (w & 1) * 64 + rl) * KBY + kbsw;
  const char* pB = (const char*)xt + (size_t)b * XTIMG_B
                 + (size_t)(2 * ho) * XTROW_B
                 + (2 * ((w & 1) * 64 + rl)) * 256 + kbsw;
  char* sbase = ((w < 2) ? sA : sB) + (w & 1) * 8192;

  const int fr = l & 15;
  const int kq = (l >> 4) << 4;
  const int wm = (w >> 1) * 64;
  const int wn = (w & 1) * 64;

  f32x4 acc[4][4];
  #pragma unroll
  for (int a = 0; a < 4; a++)
    #pragma unroll
    for (int c = 0; c < 4; c++) acc[a][c] = (f32x4)(0.f);

  for (int kt = 0; kt < NTK; kt++) {
    __syncthreads();
    if (w < 2) {
      const char* pa = gA + kt * 128;
      #pragma unroll
      for (int j = 0; j < 8; j++)
        __builtin_amdgcn_global_load_lds((gcu32*)(pa + (size_t)j * 8 * KBY),
                                         (slu32*)(sbase + j * 1024), 16, 0, 0);
    } else {
      int tap = kt >> 1;
      int kh = tap / 3, kw = tap - 3 * kh;
      const char* pb = pB + kh * XTROW_B + kw * 256 + (kt & 1) * 128;
      #pragma unroll
      for (int j = 0; j < 8; j++)
        __builtin_amdgcn_global_load_lds((gcu32*)(pb + j * 4096),
                                         (slu32*)(sbase + j * 1024), 16, 0, 0);
    }
    __syncthreads();

    #pragma unroll
    for (int kk = 0; kk < 2; kk++) {
      short8 af[4], bf[4];
      #pragma unroll
      for (int mi = 0; mi < 4; mi++) {
        int row = wm + mi * 16 + fr;
        af[mi] = *(const short8*)(sA + row * 128 + ((kk * 64 + kq) ^ ((row & 7) << 4)));
      }
      #pragma unroll
      for (int ni = 0; ni < 4; ni++) {
        int row = wn + ni * 16 + fr;
        bf[ni] = *(const short8*)(sB + row * 128 + ((kk * 64 + kq) ^ ((row & 7) << 4)));
      }
      #pragma unroll
      for (int mi = 0; mi < 4; mi++)
        #pragma unroll
        for (int ni = 0; ni < 4; ni++)
          asm("v_mfma_f32_16x16x32_bf16 %0, %1, %2, %0"
              : "+v"(acc[mi][ni]) : "v"(af[mi]), "v"(bf[ni]));
    }
  }

  // epilogue: m = m0+wm+mi*16+(l>>4)*4+r, n = n0+wn+ni*16+(l&15)
  const int nl0 = (n0 & 16383) + wn;
  const int rq = (l >> 4) * 4;
  #pragma unroll
  for (int mi = 0; mi < 4; mi++) {
    #pragma unroll
    for (int r = 0; r < 4; r++) {
      int m = m0 + wm + mi * 16 + rq + r;
      if (m < 1728) {
        bool ismk = (m >= CO_OFF);
        float bias = ismk ? b_msk[m - CO_OFF] : b_off[m];
        unsigned short* dst = ismk
            ? mask + (((size_t)(b * CO_MSK + (m - CO_OFF))) << 14)
            : offs + (((size_t)(b * CO_OFF + m)) << 14);
        #pragma unroll
        for (int ni = 0; ni < 4; ni++) {
          float v = acc[mi][ni][r] + bias;
          if (ismk) v = 1.f / (1.f + expf(-v));
          dst[nl0 + ni * 16 + fr] = f2b(v);
        }
      }
    }
  }
}

// ---------------------------------------------------------------------------
// Deformable gather + per-group 2x2x9 einsum, reading xt2 (per-group
// channels-last bf16, zero-padded). One 4-B load yields both group channels;
// lane-consecutive wo -> 8-B address stride (coalesced gather). Clamp to
// [-1,256] reproduces reference validity masking exactly. Branch-free.
// ---------------------------------------------------------------------------
__global__ __launch_bounds__(256) void deform(
    const unsigned short* __restrict__ xt2, const unsigned short* __restrict__ offs,
    const unsigned short* __restrict__ mask, const float* __restrict__ wd,
    float* __restrict__ out)
{
  const int bid = blockIdx.x;               // B * G * (HO/2) = 8192
  const int hp = bid & 63;
  const int g  = (bid >> 6) & 63;
  const int b  = bid >> 12;
  const int tid = threadIdx.x;
  const int wo = tid & 127;
  const int ho = hp * 2 + (tid >> 7);

  __shared__ float swd[36];                 // [o(2)][cg(2)][k(9)]
  if (tid < 36) swd[tid] = wd[g * 36 + tid];
  __syncthreads();

  const char* bb = (const char*)xt2 + (size_t)(b * 64 + g) * XT2G_B;
  float acc0 = 0.f, acc1 = 0.f;
  const int pbase = ((b * CO_OFF + g * 18) * HO + ho) * WO + wo;
  const int mbase = ((b * CO_MSK + g * 9) * HO + ho) * WO + wo;

  #pragma unroll
  for (int k = 0; k < 9; k++) {
    float dy = b2f(offs[pbase + (2 * k) * 16384]);
    float dx = b2f(offs[pbase + (2 * k + 1) * 16384]);
    float m  = b2f(mask[mbase + k * 16384]);
    float py = dy + (float)(ho * 2 - 1 + k / 3);
    float px = dx + (float)(wo * 2 - 1 + k % 3);
    float y0f = floorf(py), x0f = floorf(px);
    float wy = py - y0f, wx = px - x0f;
    int iy0 = (int)fminf(fmaxf(y0f,       -1.f), 256.f) + 1;
    int iy1 = (int)fminf(fmaxf(y0f + 1.f, -1.f), 256.f) + 1;
    int ix0 = (int)fminf(fmaxf(x0f,       -1.f), 256.f) + 1;
    int ix1 = (int)fminf(fmaxf(x0f + 1.f, -1.f), 256.f) + 1;
    const char* r0 = bb + (size_t)iy0 * XT2ROW_B;
    const char* r1 = bb + (size_t)iy1 * XT2ROW_B;
    unsigned u00 = *(const unsigned*)(r0 + ix0 * 4);
    unsigned u01 = *(const unsigned*)(r0 + ix1 * 4);
    unsigned u10 = *(const unsigned*)(r1 + ix0 * 4);
    unsigned u11 = *(const unsigned*)(r1 + ix1 * 4);
    float w11 = wy * wx;
    float w10 = wy - w11;
    float w01 = wx - w11;
    float w00 = 1.f - wy - w01;
    float v0 = w00 * b2f((unsigned short)u00) + w01 * b2f((unsigned short)u01)
             + w10 * b2f((unsigned short)u10) + w11 * b2f((unsigned short)u11);
    float v1 = w00 * b2f((unsigned short)(u00 >> 16)) + w01 * b2f((unsigned short)(u01 >> 16))
             + w10 * b2f((unsigned short)(u10 >> 16)) + w11 * b2f((unsigned short)(u11 >> 16));
    acc0 += m * (swd[k] * v0 + swd[9 + k] * v1);
    acc1 += m * (swd[18 + k] * v0 + swd[27 + k] * v1);
  }

  out[((size_t)(b * CIN + g * 2 + 0) * HO + ho) * WO + wo] = acc0;
  out[((size_t)(b * CIN + g * 2 + 1) * HO + ho) * WO + wo] = acc1;
}

extern "C" void kernel_launch(void* const* d_in, const int* in_sizes, int n_in,
                              void* d_out, int out_size, void* d_ws, size_t ws_size,
                              hipStream_t stream) {
  const float* x     = (const float*)d_in[0];
  const float* w_off = (const float*)d_in[1];
  const float* b_off = (const float*)d_in[2];
  const float* w_msk = (const float*)d_in[3];
  const float* b_msk = (const float*)d_in[4];
  const float* w_def = (const float*)d_in[5];
  float* out = (float*)d_out;

  unsigned short* xt   = (unsigned short*)d_ws;                 // 34.1 MB
  unsigned short* xt2  = xt  + (size_t)B_SZ * 258 * 258 * CIN;  // 34.1 MB
  unsigned short* wbf  = xt2 + (size_t)B_SZ * 258 * 258 * CIN;  // 4.1 MB
  unsigned short* offs = wbf + (size_t)MPAD * KD;               // 75.5 MB
  unsigned short* mask = offs + (size_t)B_SZ * CO_OFF * HO * WO;// 37.7 MB

  xpose<<<B_SZ * 258, 256, 0, stream>>>(x, xt, xt2);
  pack_w<<<(MPAD * KD) / 256, 256, 0, stream>>>(w_off, w_msk, wbf);
  gemm_conv<<<14 * 256, 256, 0, stream>>>(wbf, xt, b_off, b_msk, offs, mask);
  deform<<<B_SZ * NG * (HO / 2), 256, 0, stream>>>(xt2, offs, mask, w_def, out);
}

// Round 9
// 339.950 us; speedup vs baseline: 1.0450x; 1.0450x over previous
//
#include <hip/hip_runtime.h>
#include <math.h>

#define B_SZ 2
#define H_IN 256
#define W_IN 256
#define HO 128
#define WO 128
#define CIN 128
#define CO_OFF 1152
#define CO_MSK 576
#define NG 64
#define KD 1152           // GEMM K, reordered: k = (kh*3+kw)*128 + ci
#define KBY 2304          // K row bytes in bf16
#define ND 32768          // GEMM N = B*HO*WO
#define MPAD 1792         // 1728 padded to 14*128
#define NTK 18            // K-tiles (1152/64)
#define XTROW_B 66048     // 258*128*2 bytes per padded iy row (GEMM layout)
#define XTIMG_B 17040384  // 258*XTROW_B bytes per image
#define XT2ROW_B 1032     // 258*2ch*2B per iy row (deform layout, per group)
#define XT2G_B 266256     // 258*XT2ROW_B per (b,g) plane
#define XT2IMG_B 17040384 // 64*XT2G_B per image

typedef short short8 __attribute__((ext_vector_type(8)));
typedef float f32x4 __attribute__((ext_vector_type(4)));
typedef const unsigned int __attribute__((address_space(1))) gcu32;
typedef unsigned int __attribute__((address_space(3))) slu32;

__device__ __forceinline__ unsigned short f2b(float v) {
  union { float f; unsigned u; } a; a.f = v;
  unsigned r = a.u + 0x7FFF + ((a.u >> 16) & 1);
  return (unsigned short)(r >> 16);
}
__device__ __forceinline__ float b2f(unsigned short u) {
  union { unsigned u; float f; } a; a.u = ((unsigned)u) << 16;
  return a.f;
}

// ---------------------------------------------------------------------------
// x (NCHW f32) -> xt  [b][iy+1][ix+1][ci]        bf16 (GEMM B operand)
//              -> xt2 [b][g][iy+1][ix+1][c{0,1}] bf16 (deform gather layout)
// One block per (b, iy_t); full 128ci x 256ix row staged once in LDS (bf16),
// single barrier, both layouts emitted coalesced.
// ---------------------------------------------------------------------------
__global__ __launch_bounds__(256) void xpose(const float* __restrict__ x,
                                             unsigned short* __restrict__ xt,
                                             unsigned short* __restrict__ xt2) {
  const int bid = blockIdx.x;            // 2*258
  const int iyt = bid % 258;
  const int b = bid / 258;
  const int tid = threadIdx.x;
  char* rowp = (char*)xt  + (size_t)b * XTIMG_B  + (size_t)iyt * XTROW_B;
  char* x2b  = (char*)xt2 + (size_t)b * XT2IMG_B + (size_t)iyt * XT2ROW_B;
  const int iy = iyt - 1;
  const short8 z8 = {0, 0, 0, 0, 0, 0, 0, 0};

  if (iy < 0 || iy >= H_IN) {            // full zero row in both tensors
    for (int i = tid; i < 4128; i += 256)
      *reinterpret_cast<short8*>(rowp + i * 16) = z8;
    for (int i = tid; i < 16512; i += 256) {   // 64 g x 258 ix, 4B each
      int g = i / 258, ix = i - g * 258;
      *reinterpret_cast<unsigned*>(x2b + (size_t)g * XT2G_B + ix * 4) = 0u;
    }
    return;
  }
  if (tid < 32) {                        // xt: ix = -1 and 256 pad columns
    int c = tid & 15;
    *reinterpret_cast<short8*>(rowp + ((tid >> 4) ? 257 * 256 : 0) + c * 16) = z8;
  }
  if (tid < 128) {                       // xt2 pad columns: 64 g x 2 cols
    int g = tid >> 1, c = tid & 1;
    *reinterpret_cast<unsigned*>(x2b + (size_t)g * XT2G_B + (c ? 257 : 0) * 4) = 0u;
  }

  __shared__ unsigned short S[128][256];   // 64 KB, [ci][ix] bf16
  const float* xb = x + (size_t)b * CIN * 65536 + (size_t)iy * 256;

  // stage: 128 ci x 64 float4, lane-consecutive ix -> 1KB/instr coalesced
  #pragma unroll
  for (int i = 0; i < 32; i++) {
    int id = i * 256 + tid;
    int ci = id >> 6;
    int f4 = id & 63;
    float4 v = *reinterpret_cast<const float4*>(xb + (size_t)ci * 65536 + f4 * 4);
    unsigned lo = (unsigned)f2b(v.x) | ((unsigned)f2b(v.y) << 16);
    unsigned hi = (unsigned)f2b(v.z) | ((unsigned)f2b(v.w) << 16);
    *reinterpret_cast<uint2*>(&S[ci][f4 * 4]) = make_uint2(lo, hi);
  }
  __syncthreads();

  // xt [ix][ci]: 16 iters x short8 (16B) stores, lane-consecutive ix
  #pragma unroll
  for (int i = 0; i < 16; i++) {
    int id = i * 256 + tid;
    int ix = id & 255, cg = id >> 8;
    short8 o;
    #pragma unroll
    for (int e = 0; e < 8; e++) o[e] = (short)S[cg * 8 + e][ix];
    *reinterpret_cast<short8*>(rowp + (ix + 1) * 256 + cg * 16) = o;
  }

  // xt2 [g][ix][c2]: 64 iters, each instr writes a contiguous 1KB g-row
  #pragma unroll 4
  for (int g = 0; g < 64; g++) {
    unsigned u = (unsigned)S[2 * g][tid] | ((unsigned)S[2 * g + 1][tid] << 16);
    *reinterpret_cast<unsigned*>(x2b + (size_t)g * XT2G_B + (tid + 1) * 4) = u;
  }
}

// ---------------------------------------------------------------------------
// Pack weights bf16 [MPAD][KD], K reordered: wb[m][tap*128+ci] = w[m][ci*9+tap]
// ---------------------------------------------------------------------------
__global__ __launch_bounds__(256) void pack_w(const float* __restrict__ w_off,
                                              const float* __restrict__ w_msk,
                                              unsigned short* __restrict__ wb) {
  int i = blockIdx.x * 256 + threadIdx.x;        // MPAD*KD exact
  int m = i / KD;
  int k = i - m * KD;
  int tap = k >> 7, ci = k & 127;
  int src = ci * 9 + tap;
  float v = 0.f;
  if (m < CO_OFF) v = w_off[(size_t)m * KD + src];
  else if (m < 1728) v = w_msk[(size_t)(m - CO_OFF) * KD + src];
  wb[i] = f2b(v);
}

// ---------------------------------------------------------------------------
// MFMA GEMM (round-2 proven structure): 128x128 tile, BK=64, 4 waves,
// single 32 KiB LDS buffer, sync-stage-sync-compute. B staged directly from
// xt (implicit conv). Both-sides XOR swizzle (row&7)<<4. Epilogue fuses
// bias + sigmoid, bf16 store.
// ---------------------------------------------------------------------------
__global__ __launch_bounds__(256, 2) void gemm_conv(
    const unsigned short* __restrict__ wb, const unsigned short* __restrict__ xt,
    const float* __restrict__ b_off, const float* __restrict__ b_msk,
    unsigned short* __restrict__ offs, unsigned short* __restrict__ mask)
{
  __shared__ __attribute__((aligned(128))) char sA[16384];   // [128 m][64 k] bf16, swizzled
  __shared__ __attribute__((aligned(128))) char sB[16384];   // [128 n][64 k] bf16, swizzled

  // XCD-aware bijective swizzle (3584 % 8 == 0, 448 per XCD)
  const int bid = blockIdx.x;
  const int swz = (bid & 7) * 448 + (bid >> 3);
  const int m0 = (swz % 14) * 128;
  const int n0 = (swz / 14) * 128;
  const int ho = (n0 >> 7) & 127;
  const int b  = n0 >> 14;

  const int tid = threadIdx.x;
  const int l = tid & 63;
  const int w = tid >> 6;

  // staging: waves 0,1 -> A halves; waves 2,3 -> B halves. 8 chunks of 8 rows.
  const int rl = l >> 3;                          // row within chunk
  const int kbsw = ((l & 7) << 4) ^ (rl << 4);    // inverse-swizzled src k-byte
  const char* gA = (const char*)wb + (size_t)(m0 + (w & 1) * 64 + rl) * KBY + kbsw;
  const char* pB = (const char*)xt + (size_t)b * XTIMG_B
                 + (size_t)(2 * ho) * XTROW_B
                 + (2 * ((w & 1) * 64 + rl)) * 256 + kbsw;
  char* sbase = ((w < 2) ? sA : sB) + (w & 1) * 8192;

  const int fr = l & 15;
  const int kq = (l >> 4) << 4;
  const int wm = (w >> 1) * 64;
  const int wn = (w & 1) * 64;

  f32x4 acc[4][4];
  #pragma unroll
  for (int a = 0; a < 4; a++)
    #pragma unroll
    for (int c = 0; c < 4; c++) acc[a][c] = (f32x4)(0.f);

  for (int kt = 0; kt < NTK; kt++) {
    __syncthreads();
    if (w < 2) {
      const char* pa = gA + kt * 128;
      #pragma unroll
      for (int j = 0; j < 8; j++)
        __builtin_amdgcn_global_load_lds((gcu32*)(pa + (size_t)j * 8 * KBY),
                                         (slu32*)(sbase + j * 1024), 16, 0, 0);
    } else {
      int tap = kt >> 1;
      int kh = tap / 3, kw = tap - 3 * kh;
      const char* pb = pB + kh * XTROW_B + kw * 256 + (kt & 1) * 128;
      #pragma unroll
      for (int j = 0; j < 8; j++)
        __builtin_amdgcn_global_load_lds((gcu32*)(pb + j * 4096),
                                         (slu32*)(sbase + j * 1024), 16, 0, 0);
    }
    __syncthreads();

    #pragma unroll
    for (int kk = 0; kk < 2; kk++) {
      short8 af[4], bf[4];
      #pragma unroll
      for (int mi = 0; mi < 4; mi++) {
        int row = wm + mi * 16 + fr;
        af[mi] = *(const short8*)(sA + row * 128 + ((kk * 64 + kq) ^ ((row & 7) << 4)));
      }
      #pragma unroll
      for (int ni = 0; ni < 4; ni++) {
        int row = wn + ni * 16 + fr;
        bf[ni] = *(const short8*)(sB + row * 128 + ((kk * 64 + kq) ^ ((row & 7) << 4)));
      }
      #pragma unroll
      for (int mi = 0; mi < 4; mi++)
        #pragma unroll
        for (int ni = 0; ni < 4; ni++)
          asm("v_mfma_f32_16x16x32_bf16 %0, %1, %2, %0"
              : "+v"(acc[mi][ni]) : "v"(af[mi]), "v"(bf[ni]));
    }
  }

  // epilogue: m = m0+wm+mi*16+(l>>4)*4+r, n = n0+wn+ni*16+(l&15)
  const int nl0 = (n0 & 16383) + wn;
  const int rq = (l >> 4) * 4;
  #pragma unroll
  for (int mi = 0; mi < 4; mi++) {
    #pragma unroll
    for (int r = 0; r < 4; r++) {
      int m = m0 + wm + mi * 16 + rq + r;
      if (m < 1728) {
        bool ismk = (m >= CO_OFF);
        float bias = ismk ? b_msk[m - CO_OFF] : b_off[m];
        unsigned short* dst = ismk
            ? mask + (((size_t)(b * CO_MSK + (m - CO_OFF))) << 14)
            : offs + (((size_t)(b * CO_OFF + m)) << 14);
        #pragma unroll
        for (int ni = 0; ni < 4; ni++) {
          float v = acc[mi][ni][r] + bias;
          if (ismk) v = 1.f / (1.f + expf(-v));
          dst[nl0 + ni * 16 + fr] = f2b(v);
        }
      }
    }
  }
}

// ---------------------------------------------------------------------------
// Deformable gather + per-group 2x2x9 einsum, reading xt2.
// Round-9 changes: (1) XCD-chunked block swizzle so blocks sharing a (b,g)
// plane run on the same XCD (L2-local gathers); (2) three-pass structure:
// all offs/mask loads -> all 36 gathers -> all arithmetic, maximizing MLP.
// ---------------------------------------------------------------------------
__global__ __launch_bounds__(256) void deform(
    const unsigned short* __restrict__ xt2, const unsigned short* __restrict__ offs,
    const unsigned short* __restrict__ mask, const float* __restrict__ wd,
    float* __restrict__ out)
{
  const int bid0 = blockIdx.x;              // 8192 = B*G*(HO/2), 8192 % 8 == 0
  const int bid = (bid0 & 7) * 1024 + (bid0 >> 3);   // bijective XCD chunking
  const int hp = bid & 63;
  const int g  = (bid >> 6) & 63;
  const int b  = bid >> 12;
  const int tid = threadIdx.x;
  const int wo = tid & 127;
  const int ho = hp * 2 + (tid >> 7);

  __shared__ float swd[36];                 // [o(2)][cg(2)][k(9)]
  if (tid < 36) swd[tid] = wd[g * 36 + tid];
  __syncthreads();

  const char* bb = (const char*)xt2 + (size_t)(b * 64 + g) * XT2G_B;
  const int pbase = ((b * CO_OFF + g * 18) * HO + ho) * WO + wo;
  const int mbase = ((b * CO_MSK + g * 9) * HO + ho) * WO + wo;

  // pass 1: all offset/mask loads (27 independent coalesced loads)
  float dyv[9], dxv[9], mv[9];
  #pragma unroll
  for (int k = 0; k < 9; k++) {
    dyv[k] = b2f(offs[pbase + (2 * k) * 16384]);
    dxv[k] = b2f(offs[pbase + (2 * k + 1) * 16384]);
    mv[k]  = b2f(mask[mbase + k * 16384]);
  }

  // pass 2: all 36 gathers in flight
  unsigned u[9][4];
  float wyv[9], wxv[9];
  #pragma unroll
  for (int k = 0; k < 9; k++) {
    float py = dyv[k] + (float)(ho * 2 - 1 + k / 3);
    float px = dxv[k] + (float)(wo * 2 - 1 + k % 3);
    float y0f = floorf(py), x0f = floorf(px);
    wyv[k] = py - y0f;
    wxv[k] = px - x0f;
    int iy0 = (int)fminf(fmaxf(y0f,       -1.f), 256.f) + 1;
    int iy1 = (int)fminf(fmaxf(y0f + 1.f, -1.f), 256.f) + 1;
    int ix0 = (int)fminf(fmaxf(x0f,       -1.f), 256.f) + 1;
    int ix1 = (int)fminf(fmaxf(x0f + 1.f, -1.f), 256.f) + 1;
    const char* r0 = bb + (size_t)iy0 * XT2ROW_B;
    const char* r1 = bb + (size_t)iy1 * XT2ROW_B;
    u[k][0] = *(const unsigned*)(r0 + ix0 * 4);
    u[k][1] = *(const unsigned*)(r0 + ix1 * 4);
    u[k][2] = *(const unsigned*)(r1 + ix0 * 4);
    u[k][3] = *(const unsigned*)(r1 + ix1 * 4);
  }

  // pass 3: bilinear + einsum
  float acc0 = 0.f, acc1 = 0.f;
  #pragma unroll
  for (int k = 0; k < 9; k++) {
    float wy = wyv[k], wx = wxv[k];
    float w11 = wy * wx;
    float w10 = wy - w11;
    float w01 = wx - w11;
    float w00 = 1.f - wy - w01;
    float v0 = w00 * b2f((unsigned short)u[k][0]) + w01 * b2f((unsigned short)u[k][1])
             + w10 * b2f((unsigned short)u[k][2]) + w11 * b2f((unsigned short)u[k][3]);
    float v1 = w00 * b2f((unsigned short)(u[k][0] >> 16)) + w01 * b2f((unsigned short)(u[k][1] >> 16))
             + w10 * b2f((unsigned short)(u[k][2] >> 16)) + w11 * b2f((unsigned short)(u[k][3] >> 16));
    acc0 += mv[k] * (swd[k] * v0 + swd[9 + k] * v1);
    acc1 += mv[k] * (swd[18 + k] * v0 + swd[27 + k] * v1);
  }

  out[((size_t)(b * CIN + g * 2 + 0) * HO + ho) * WO + wo] = acc0;
  out[((size_t)(b * CIN + g * 2 + 1) * HO + ho) * WO + wo] = acc1;
}

extern "C" void kernel_launch(void* const* d_in, const int* in_sizes, int n_in,
                              void* d_out, int out_size, void* d_ws, size_t ws_size,
                              hipStream_t stream) {
  const float* x     = (const float*)d_in[0];
  const float* w_off = (const float*)d_in[1];
  const float* b_off = (const float*)d_in[2];
  const float* w_msk = (const float*)d_in[3];
  const float* b_msk = (const float*)d_in[4];
  const float* w_def = (const float*)d_in[5];
  float* out = (float*)d_out;

  unsigned short* xt   = (unsigned short*)d_ws;                 // 34.1 MB
  unsigned short* xt2  = xt  + (size_t)B_SZ * 258 * 258 * CIN;  // 34.1 MB
  unsigned short* wbf  = xt2 + (size_t)B_SZ * 258 * 258 * CIN;  // 4.1 MB
  unsigned short* offs = wbf + (size_t)MPAD * KD;               // 75.5 MB
  unsigned short* mask = offs + (size_t)B_SZ * CO_OFF * HO * WO;// 37.7 MB

  xpose<<<B_SZ * 258, 256, 0, stream>>>(x, xt, xt2);
  pack_w<<<(MPAD * KD) / 256, 256, 0, stream>>>(w_off, w_msk, wbf);
  gemm_conv<<<14 * 256, 256, 0, stream>>>(wbf, xt, b_off, b_msk, offs, mask);
  deform<<<B_SZ * NG * (HO / 2), 256, 0, stream>>>(xt2, offs, mask, w_def, out);
}